// Round 1
// baseline (180.613 us; speedup 1.0000x reference)
//
#include <hip/hip_runtime.h>

#define BB 4
#define NN 8192            // NP == NG == 8192
#define TILE 1024
#define CH (NN / TILE)     // 8 chunks
#define PB (NN / 256)      // 32 point-blocks

// ---------------- K1: repack to SoA, mask invalid gt, init mins ----------------
__global__ __launch_bounds__(256) void k_init(
    const float* __restrict__ pr, const float* __restrict__ gt,
    const int* __restrict__ valid,
    float* __restrict__ gtp, float* __restrict__ prp,
    float* __restrict__ mac, float* __restrict__ mco) {
  int i = blockIdx.x * 256 + threadIdx.x;       // 0 .. BB*NN
  if (i >= BB * NN) return;
  int b = i >> 13;        // /8192
  int g = i & (NN - 1);
  const float BIG = 1e18f;
  int vld = valid[i] != 0;
  float gx = gt[i * 3 + 0], gy = gt[i * 3 + 1], gz = gt[i * 3 + 2];
  float* gb = gtp + (size_t)b * 3 * NN;
  gb[0 * NN + g] = vld ? gx : BIG;
  gb[1 * NN + g] = vld ? gy : BIG;
  gb[2 * NN + g] = vld ? gz : BIG;
  float px = pr[i * 3 + 0], py = pr[i * 3 + 1], pz = pr[i * 3 + 2];
  float* pb = prp + (size_t)b * 3 * NN;
  pb[0 * NN + g] = px;
  pb[1 * NN + g] = py;
  pb[2 * NN + g] = pz;
  mac[i] = __int_as_float(0x7F800000);          // +inf
  mco[i] = __int_as_float(0x7F800000);
}

// ---------------- K2: fused bidirectional min-distance pass ----------------
// blockIdx bits: dir(1) | chunk(3) | pblock(5) | batch(2)  -> 2048 blocks
__global__ __launch_bounds__(256) void k_dist(
    const float* __restrict__ gtp, const float* __restrict__ prp,
    float* __restrict__ mac, float* __restrict__ mco) {
  __shared__ float sx[TILE], sy[TILE], sz[TILE];
  int id = blockIdx.x;
  int dir = id & 1; id >>= 1;
  int c   = id & (CH - 1); id >>= 3;
  int pb  = id & (PB - 1); id >>= 5;
  int b   = id;
  int tid = threadIdx.x;

  const float* own   = dir ? gtp : prp;
  const float* other = dir ? prp : gtp;
  float*       marr  = dir ? mco : mac;

  // stage 1024-point SoA tile of the "other" side
  const float* op = other + (size_t)b * 3 * NN + c * TILE;
  *(float4*)&sx[4 * tid] = *(const float4*)(op + 0 * NN + 4 * tid);
  *(float4*)&sy[4 * tid] = *(const float4*)(op + 1 * NN + 4 * tid);
  *(float4*)&sz[4 * tid] = *(const float4*)(op + 2 * NN + 4 * tid);

  int p = pb * 256 + tid;
  const float* ow = own + (size_t)b * 3 * NN;
  float px = ow[0 * NN + p], py = ow[1 * NN + p], pz = ow[2 * NN + p];
  __syncthreads();

  float m = __int_as_float(0x7F800000);
  const float4* vx = (const float4*)sx;
  const float4* vy = (const float4*)sy;
  const float4* vz = (const float4*)sz;
#pragma unroll 4
  for (int j = 0; j < TILE / 4; ++j) {
    float4 X = vx[j], Y = vy[j], Z = vz[j];
    float dx, dy, dz, d0, d1, d2, d3;
    dx = px - X.x; dy = py - Y.x; dz = pz - Z.x;
    d0 = fmaf(dx, dx, fmaf(dy, dy, dz * dz));
    dx = px - X.y; dy = py - Y.y; dz = pz - Z.y;
    d1 = fmaf(dx, dx, fmaf(dy, dy, dz * dz));
    dx = px - X.z; dy = py - Y.z; dz = pz - Z.z;
    d2 = fmaf(dx, dx, fmaf(dy, dy, dz * dz));
    dx = px - X.w; dy = py - Y.w; dz = pz - Z.w;
    d3 = fmaf(dx, dx, fmaf(dy, dy, dz * dz));
    m = fminf(m, fminf(fminf(d0, d1), fminf(d2, d3)));
  }
  // squared distances are >= 0, so int-compare == float-compare
  atomicMin((int*)&marr[(size_t)b * NN + p], __float_as_int(m));
}

// ---------------- K3: per-batch reductions ----------------
__global__ __launch_bounds__(256) void k_batch(
    const float* __restrict__ mac, const float* __restrict__ mco,
    const int* __restrict__ valid, float* __restrict__ res) {
  int b = blockIdx.x, tid = threadIdx.x;
  float sa = 0.f, sc = 0.f, cn = 0.f;
  for (int i = tid; i < NN; i += 256) {
    sa += mac[(size_t)b * NN + i];
    if (valid[(size_t)b * NN + i] != 0) {
      sc += mco[(size_t)b * NN + i];
      cn += 1.0f;
    }
  }
  __shared__ float r1[256], r2[256], r3[256];
  r1[tid] = sa; r2[tid] = sc; r3[tid] = cn;
  __syncthreads();
  for (int off = 128; off > 0; off >>= 1) {
    if (tid < off) {
      r1[tid] += r1[tid + off];
      r2[tid] += r2[tid + off];
      r3[tid] += r3[tid + off];
    }
    __syncthreads();
  }
  if (tid == 0) {
    res[b]      = r1[0] / (float)NN;            // acc_b
    res[BB + b] = r2[0] / fmaxf(r3[0], 1.0f);   // com_b
  }
}

// ---------------- K4: final scalar ----------------
__global__ void k_final(const float* __restrict__ res, float* __restrict__ out) {
  if (threadIdx.x == 0 && blockIdx.x == 0) {
    float a = 0.f, c = 0.f;
    for (int b = 0; b < BB; ++b) { a += res[b]; c += res[BB + b]; }
    a *= 0.25f; c *= 0.25f;
    out[0] = 2.0f * (a + c);   // loss_acc + loss_com + loss_cd
  }
}

extern "C" void kernel_launch(void* const* d_in, const int* in_sizes, int n_in,
                              void* d_out, int out_size, void* d_ws, size_t ws_size,
                              hipStream_t stream) {
  const float* pr    = (const float*)d_in[0];   // [4,8192,3] f32
  const float* gt    = (const float*)d_in[1];   // [4,8192,3] f32
  const int*   valid = (const int*)d_in[2];     // [4,8192] int (bool)

  float* ws  = (float*)d_ws;
  float* gtp = ws;                              // BB*3*NN
  float* prp = gtp + (size_t)BB * 3 * NN;       // BB*3*NN
  float* mac = prp + (size_t)BB * 3 * NN;       // BB*NN
  float* mco = mac + (size_t)BB * NN;           // BB*NN
  float* res = mco + (size_t)BB * NN;           // 2*BB

  k_init<<<(BB * NN) / 256, 256, 0, stream>>>(pr, gt, valid, gtp, prp, mac, mco);
  k_dist<<<2 * CH * PB * BB, 256, 0, stream>>>(gtp, prp, mac, mco);
  k_batch<<<BB, 256, 0, stream>>>(mac, mco, valid, res);
  k_final<<<1, 64, 0, stream>>>(res, (float*)d_out);
}

// Round 2
// 115.061 us; speedup vs baseline: 1.5697x; 1.5697x over previous
//
#include <hip/hip_runtime.h>

#define BB 4
#define NN 8192
#define CHUNKS 16
#define TILE (NN / CHUNKS)        // 512 other-points per chunk
#define ROWN 8                    // own points per thread
#define OWNB (NN / (256 * ROWN))  // 4 own-blocks per (dir,b)

// ws layout (floats)
#define OFF_TG 0
#define OFF_TP (BB * NN * 4)
#define OFF_PART (2 * BB * NN * 4)
#define NPART (2 * BB * CHUNKS * NN)
#define OFF_RES (OFF_PART + NPART)

// ---------- K1: pack float4(x,y,z,|.|^2) per point; mask invalid gt; zero res ----------
__global__ __launch_bounds__(256) void k_init(
    const float* __restrict__ pr, const float* __restrict__ gt,
    const int* __restrict__ valid, float4* __restrict__ Tg,
    float4* __restrict__ Tp, float* __restrict__ res) {
  int i = blockIdx.x * 256 + threadIdx.x;
  if (blockIdx.x == 0 && threadIdx.x < 16) res[threadIdx.x] = 0.0f;
  if (i >= BB * NN) return;
  float gx = gt[i * 3 + 0], gy = gt[i * 3 + 1], gz = gt[i * 3 + 2];
  float sg = gx * gx + gy * gy + gz * gz;
  Tg[i] = make_float4(gx, gy, gz, valid[i] != 0 ? sg : 1e30f);
  float px = pr[i * 3 + 0], py = pr[i * 3 + 1], pz = pr[i * 3 + 2];
  float sp = px * px + py * py + pz * pz;
  Tp[i] = make_float4(px, py, pz, sp);
}

// ---------- K2: partial-min distance pass ----------
// grid bits: dir(1) | b(2) | ownblk(2) | chunk(4)  -> 2*4*4*16 = 512 blocks
__global__ __launch_bounds__(256) void k_dist(
    const float4* __restrict__ Tg, const float4* __restrict__ Tp,
    float* __restrict__ part) {
  __shared__ float4 lt[TILE];
  int id = blockIdx.x;
  int chunk = id & (CHUNKS - 1); id >>= 4;
  int ownblk = id & (OWNB - 1);  id >>= 2;
  int b = id & 3;                id >>= 2;
  int dir = id;                  // 0: own=pr,other=gt (acc); 1: own=gt,other=pr (com)
  int tid = threadIdx.x;

  const float4* own   = dir ? Tg : Tp;
  const float4* other = dir ? Tp : Tg;

  // stage 512 other points (8 KB)
  const float4* op = other + (size_t)b * NN + chunk * TILE;
  lt[tid]       = op[tid];
  lt[tid + 256] = op[tid + 256];

  // load 8 own points into registers, pre-scale by -2
  float o2x[ROWN], o2y[ROWN], o2z[ROWN], ow[ROWN], m[ROWN];
  const float4* ob = own + (size_t)b * NN + ownblk * (256 * ROWN);
#pragma unroll
  for (int r = 0; r < ROWN; ++r) {
    float4 o = ob[r * 256 + tid];
    o2x[r] = -2.0f * o.x; o2y[r] = -2.0f * o.y; o2z[r] = -2.0f * o.z;
    ow[r] = o.w;
    m[r] = 1e38f;
  }
  __syncthreads();

  for (int jt = 0; jt < TILE; jt += 4) {
    float4 T0 = lt[jt + 0], T1 = lt[jt + 1], T2 = lt[jt + 2], T3 = lt[jt + 3];
#pragma unroll
    for (int r = 0; r < ROWN; ++r) {
      float d0 = fmaf(o2x[r], T0.x, fmaf(o2y[r], T0.y, fmaf(o2z[r], T0.z, T0.w)));
      float d1 = fmaf(o2x[r], T1.x, fmaf(o2y[r], T1.y, fmaf(o2z[r], T1.z, T1.w)));
      float d2 = fmaf(o2x[r], T2.x, fmaf(o2y[r], T2.y, fmaf(o2z[r], T2.z, T2.w)));
      float d3 = fmaf(o2x[r], T3.x, fmaf(o2y[r], T3.y, fmaf(o2z[r], T3.z, T3.w)));
      m[r] = fminf(m[r], fminf(fminf(d0, d1), fminf(d2, d3)));
    }
  }

  // store partial mins (+|own|^2, constant across chunks -> commutes with min)
  float* pb = part + ((size_t)(dir * BB + b) * CHUNKS + chunk) * NN + ownblk * (256 * ROWN);
#pragma unroll
  for (int r = 0; r < ROWN; ++r) pb[r * 256 + tid] = m[r] + ow[r];
}

// ---------- K3: reduce over chunks, masked sums ----------
// grid: dir(1) | b(2) | ownblk(2) -> 32 blocks
__global__ __launch_bounds__(256) void k_red(
    const float* __restrict__ part, const int* __restrict__ valid,
    float* __restrict__ res) {
  int id = blockIdx.x;
  int ownblk = id & (OWNB - 1); id >>= 2;
  int b = id & 3;               id >>= 2;
  int dir = id;
  int tid = threadIdx.x;

  float sum = 0.0f, cnt = 0.0f;
  const float* pb = part + (size_t)(dir * BB + b) * CHUNKS * NN + ownblk * (256 * ROWN);
#pragma unroll
  for (int r = 0; r < ROWN; ++r) {
    int own = r * 256 + tid;
    float v = 1e38f;
#pragma unroll
    for (int c = 0; c < CHUNKS; ++c) v = fminf(v, pb[(size_t)c * NN + own]);
    if (dir == 0) {
      sum += v;
    } else {
      int vld = valid[(size_t)b * NN + ownblk * (256 * ROWN) + own] != 0;
      sum += vld ? v : 0.0f;
      cnt += vld ? 1.0f : 0.0f;
    }
  }
  __shared__ float r1[256], r2[256];
  r1[tid] = sum; r2[tid] = cnt;
  __syncthreads();
  for (int off = 128; off > 0; off >>= 1) {
    if (tid < off) { r1[tid] += r1[tid + off]; r2[tid] += r2[tid + off]; }
    __syncthreads();
  }
  if (tid == 0) {
    if (dir == 0) {
      atomicAdd(&res[b], r1[0]);
    } else {
      atomicAdd(&res[4 + b], r1[0]);
      atomicAdd(&res[8 + b], r2[0]);
    }
  }
}

// ---------- K4: final scalar ----------
__global__ void k_final(const float* __restrict__ res, float* __restrict__ out) {
  if (threadIdx.x == 0 && blockIdx.x == 0) {
    float a = 0.f, c = 0.f;
    for (int b = 0; b < BB; ++b) {
      a += res[b] / (float)NN;
      c += res[4 + b] / fmaxf(res[8 + b], 1.0f);
    }
    a *= 0.25f; c *= 0.25f;
    out[0] = 2.0f * (a + c);
  }
}

extern "C" void kernel_launch(void* const* d_in, const int* in_sizes, int n_in,
                              void* d_out, int out_size, void* d_ws, size_t ws_size,
                              hipStream_t stream) {
  const float* pr    = (const float*)d_in[0];
  const float* gt    = (const float*)d_in[1];
  const int*   valid = (const int*)d_in[2];

  float* ws   = (float*)d_ws;
  float4* Tg  = (float4*)(ws + OFF_TG);
  float4* Tp  = (float4*)(ws + OFF_TP);
  float* part = ws + OFF_PART;
  float* res  = ws + OFF_RES;

  k_init<<<(BB * NN) / 256, 256, 0, stream>>>(pr, gt, valid, Tg, Tp, res);
  k_dist<<<2 * BB * OWNB * CHUNKS, 256, 0, stream>>>(Tg, Tp, part);
  k_red<<<2 * BB * OWNB, 256, 0, stream>>>(part, valid, res);
  k_final<<<1, 64, 0, stream>>>(res, (float*)d_out);
}

// Round 3
// 102.172 us; speedup vs baseline: 1.7677x; 1.1262x over previous
//
#include <hip/hip_runtime.h>

#define BB 4
#define NN 8192
#define CHUNKS 16
#define TILE (NN / CHUNKS)        // 512 other-points per chunk
#define ROWN 8                    // own points per thread
#define OWNB (NN / (256 * ROWN))  // 4 own-blocks per (dir,b)

// ws layout (floats)
#define OFF_TG 0
#define OFF_TP (BB * NN * 4)
#define OFF_MAC (2 * BB * NN * 4)
#define OFF_MCO (OFF_MAC + BB * NN)
#define OFF_RES (OFF_MCO + BB * NN)

// ---------- K1: pack float4(x,y,z,|.|^2); mask invalid gt via w=1e30; init mins; zero res ----------
__global__ __launch_bounds__(256) void k_init(
    const float* __restrict__ pr, const float* __restrict__ gt,
    const int* __restrict__ valid, float4* __restrict__ Tg,
    float4* __restrict__ Tp, float* __restrict__ mac,
    float* __restrict__ mco, float* __restrict__ res) {
  int i = blockIdx.x * 256 + threadIdx.x;
  if (blockIdx.x == 0 && threadIdx.x < 16) res[threadIdx.x] = 0.0f;
  if (i >= BB * NN) return;
  float gx = gt[i * 3 + 0], gy = gt[i * 3 + 1], gz = gt[i * 3 + 2];
  float sg = gx * gx + gy * gy + gz * gz;
  Tg[i] = make_float4(gx, gy, gz, valid[i] != 0 ? sg : 1e30f);
  float px = pr[i * 3 + 0], py = pr[i * 3 + 1], pz = pr[i * 3 + 2];
  float sp = px * px + py * py + pz * pz;
  Tp[i] = make_float4(px, py, pz, sp);
  mac[i] = __int_as_float(0x7F800000);   // +inf
  mco[i] = __int_as_float(0x7F800000);
}

// ---------- K2: fused bidirectional min-distance, atomicMin output ----------
// grid bits: dir(1) | b(2) | ownblk(2) | chunk(4)  -> 512 blocks
__global__ __launch_bounds__(256, 2) void k_dist(
    const float4* __restrict__ Tg, const float4* __restrict__ Tp,
    float* __restrict__ mac, float* __restrict__ mco) {
  __shared__ float4 lt[TILE];
  int id = blockIdx.x;
  int chunk = id & (CHUNKS - 1); id >>= 4;
  int ownblk = id & (OWNB - 1);  id >>= 2;
  int b = id & 3;                id >>= 2;
  int dir = id;                  // 0: own=pr,other=gt (acc); 1: own=gt,other=pr (com)
  int tid = threadIdx.x;

  const float4* own   = dir ? Tg : Tp;
  const float4* other = dir ? Tp : Tg;
  float*        marr  = dir ? mco : mac;

  // stage 512 other points (8 KB)
  const float4* op = other + (size_t)b * NN + chunk * TILE;
  lt[tid]       = op[tid];
  lt[tid + 256] = op[tid + 256];

  // 8 own points in registers, pre-scaled by -2
  float o2x[ROWN], o2y[ROWN], o2z[ROWN], ow[ROWN], m[ROWN];
  const float4* ob = own + (size_t)b * NN + ownblk * (256 * ROWN);
#pragma unroll
  for (int r = 0; r < ROWN; ++r) {
    float4 o = ob[r * 256 + tid];
    o2x[r] = -2.0f * o.x; o2y[r] = -2.0f * o.y; o2z[r] = -2.0f * o.z;
    ow[r] = o.w;
    m[r] = 1e38f;
  }
  __syncthreads();

#pragma unroll 2
  for (int jt = 0; jt < TILE; jt += 4) {
    float4 T0 = lt[jt + 0], T1 = lt[jt + 1], T2 = lt[jt + 2], T3 = lt[jt + 3];
#pragma unroll
    for (int r = 0; r < ROWN; ++r) {
      float d0 = fmaf(o2x[r], T0.x, fmaf(o2y[r], T0.y, fmaf(o2z[r], T0.z, T0.w)));
      float d1 = fmaf(o2x[r], T1.x, fmaf(o2y[r], T1.y, fmaf(o2z[r], T1.z, T1.w)));
      float d2 = fmaf(o2x[r], T2.x, fmaf(o2y[r], T2.y, fmaf(o2z[r], T2.z, T2.w)));
      float d3 = fmaf(o2x[r], T3.x, fmaf(o2y[r], T3.y, fmaf(o2z[r], T3.z, T3.w)));
      // min-of-5 -> two v_min3_f32
      m[r] = fminf(fminf(fminf(d0, d1), d2), fminf(fminf(d3, m[r]), m[r]));
    }
  }

  // one atomicMin per own point (f32 bit pattern; values >= -eps, ordering OK)
  int p = ownblk * (256 * ROWN) + tid;
#pragma unroll
  for (int r = 0; r < ROWN; ++r)
    atomicMin((int*)&marr[(size_t)b * NN + p + r * 256], __float_as_int(m[r] + ow[r]));
}

// ---------- K3: reduce mins, masked sums ----------
// grid: dir(1) | b(2) | ownblk(2) -> 32 blocks
__global__ __launch_bounds__(256) void k_red(
    const float* __restrict__ mac, const float* __restrict__ mco,
    const int* __restrict__ valid, float* __restrict__ res) {
  int id = blockIdx.x;
  int ownblk = id & (OWNB - 1); id >>= 2;
  int b = id & 3;               id >>= 2;
  int dir = id;
  int tid = threadIdx.x;

  float sum = 0.0f, cnt = 0.0f;
#pragma unroll
  for (int r = 0; r < ROWN; ++r) {
    size_t own = (size_t)b * NN + ownblk * (256 * ROWN) + r * 256 + tid;
    if (dir == 0) {
      sum += mac[own];
    } else {
      int vld = valid[own] != 0;
      sum += vld ? mco[own] : 0.0f;
      cnt += vld ? 1.0f : 0.0f;
    }
  }
  __shared__ float r1[256], r2[256];
  r1[tid] = sum; r2[tid] = cnt;
  __syncthreads();
  for (int off = 128; off > 0; off >>= 1) {
    if (tid < off) { r1[tid] += r1[tid + off]; r2[tid] += r2[tid + off]; }
    __syncthreads();
  }
  if (tid == 0) {
    if (dir == 0) {
      atomicAdd(&res[b], r1[0]);
    } else {
      atomicAdd(&res[4 + b], r1[0]);
      atomicAdd(&res[8 + b], r2[0]);
    }
  }
}

// ---------- K4: final scalar ----------
__global__ void k_final(const float* __restrict__ res, float* __restrict__ out) {
  if (threadIdx.x == 0 && blockIdx.x == 0) {
    float a = 0.f, c = 0.f;
    for (int b = 0; b < BB; ++b) {
      a += res[b] / (float)NN;
      c += res[4 + b] / fmaxf(res[8 + b], 1.0f);
    }
    a *= 0.25f; c *= 0.25f;
    out[0] = 2.0f * (a + c);
  }
}

extern "C" void kernel_launch(void* const* d_in, const int* in_sizes, int n_in,
                              void* d_out, int out_size, void* d_ws, size_t ws_size,
                              hipStream_t stream) {
  const float* pr    = (const float*)d_in[0];
  const float* gt    = (const float*)d_in[1];
  const int*   valid = (const int*)d_in[2];

  float* ws  = (float*)d_ws;
  float4* Tg = (float4*)(ws + OFF_TG);
  float4* Tp = (float4*)(ws + OFF_TP);
  float* mac = ws + OFF_MAC;
  float* mco = ws + OFF_MCO;
  float* res = ws + OFF_RES;

  k_init<<<(BB * NN) / 256, 256, 0, stream>>>(pr, gt, valid, Tg, Tp, mac, mco, res);
  k_dist<<<2 * BB * OWNB * CHUNKS, 256, 0, stream>>>(Tg, Tp, mac, mco);
  k_red<<<2 * BB * OWNB, 256, 0, stream>>>(mac, mco, valid, res);
  k_final<<<1, 64, 0, stream>>>(res, (float*)d_out);
}